// Round 12
// baseline (195.166 us; speedup 1.0000x reference)
//
#include <hip/hip_runtime.h>

#define KNN 32
#define BLOCK 256
#define ROWS 4
#define CAP 256
#define NSLOT 128
#define TGT 64.0f

// ws layout:
//   [0 .. NSLOT*16) doubles: hashed accumulator slots, per slot c:
//     c=0..3: sum_y, sum_y2, sum_m, sum_m2
//     c=4: W   c=5: S1y=sum w*y_i*y_k  c=6: S2y=sum w*(y_i+y_k)  c=7: S1m  c=8: S2m
//   then float t_arr[N]: per-point d2 search threshold
// moran num_y = S1y - mu_y*S2y + mu_y^2*W  (mean-free expansion; exact in f64)

__device__ inline float bessel_i0f(float z) {
  if (z < 3.75f) {
    float u = z * z * (1.0f / (3.75f * 3.75f));
    return 1.0f + u * (3.5156229f + u * (3.0899424f + u * (1.2067492f +
                  u * (0.2659732f + u * (0.0360768f + u * 0.0045813f)))));
  } else {
    float w = 3.75f / z;
    float p = 0.39894228f + w * (0.01328592f + w * (0.00225319f + w * (-0.00157565f +
              w * (0.00916281f + w * (-0.02057706f + w * (0.02635537f +
              w * (-0.01647633f + w * 0.00392377f)))))));
    return __expf(z) * p * __frsqrt_rn(z);
  }
}

// d2-threshold t with E[#points: d2<t] ~= TGT for query at |q|^2=qs, points ~ N(0,I2):
// E(t) = (N/2) e^{-qs/2} * Int_0^t e^{-s/2} I0(|q| sqrt(s)) ds  (16-pt midpoint, 2 fixed-point iters)
__device__ inline float knn_threshold(float qs, int N) {
  float t = fminf(fmaxf((2.0f * TGT / (float)N) * __expf(0.5f * qs), 1e-3f), 12.0f);
  float aq = sqrtf(qs);
#pragma unroll
  for (int nit = 0; nit < 2; ++nit) {
    float dt = t * (1.0f / 16.0f);
    float acc = 0.0f;
#pragma unroll
    for (int k = 0; k < 16; ++k) {
      float s = ((float)k + 0.5f) * dt;
      acc += __expf(-0.5f * s) * bessel_i0f(aq * sqrtf(s));
    }
    float E = 0.5f * (float)N * __expf(-0.5f * qs) * acc * dt;
    t = fminf(fmaxf(t * (TGT / fmaxf(E, 1.0f)), 1e-3f), 32.0f);
  }
  return t;
}

__global__ __launch_bounds__(BLOCK) void thresh_kernel(const float4* __restrict__ x4,
                                                       float* __restrict__ t_arr, int N) {
  int j = blockIdx.x * BLOCK + threadIdx.x;
  if (j < N) {
    float4 xi = x4[j];
    float qs = xi.x * xi.x + xi.y * xi.y;
    t_arr[j] = knn_threshold(qs, N);
  }
}

__global__ __launch_bounds__(BLOCK, 4) void knn_moran_kernel(const float4* __restrict__ x4,
                                                             const float* __restrict__ y,
                                                             const float* __restrict__ m,
                                                             double* __restrict__ ws,
                                                             const float* __restrict__ t_arr,
                                                             int N) {
  __shared__ unsigned long long s_cand[ROWS][CAP];
  __shared__ int s_count[ROWS];
  __shared__ float s_tf[ROWS];  // fallback thresholds live in LDS (cold path)
  __shared__ float s_sel_d2[ROWS][KNN];
  __shared__ int s_sel_i[ROWS][KNN];
  __shared__ double s_part[BLOCK / 64][5];
  __shared__ double s_ysum[4];

  const int i0 = blockIdx.x * ROWS;
  const int tid = threadIdx.x;
  const int lane = tid & 63;
  const int wid = tid >> 6;

  if (tid < ROWS) s_count[tid] = 0;

  // fold this block's slice of the global y/m sums (4 elements)
  if (tid < ROWS) {
    double yv = (double)y[i0 + tid], mv = (double)m[i0 + tid];
    double a = yv, b = yv * yv, c = mv, d = mv * mv;
    for (int off = 2; off > 0; off >>= 1) {
      a += __shfl_down(a, off, 4);
      b += __shfl_down(b, off, 4);
      c += __shfl_down(c, off, 4);
      d += __shfl_down(d, off, 4);
    }
    if (tid == 0) { s_ysum[0] = a; s_ysum[1] = b; s_ysum[2] = c; s_ysum[3] = d; }
  }

  float qx[ROWS], qy[ROWS], qs[ROWS];
  unsigned lim[ROWS];  // candidate <=> bits(d2) < lim  (positive floats: bit order = numeric)
#pragma unroll
  for (int r = 0; r < ROWS; ++r) {
    float4 xi = x4[i0 + r];
    qx[r] = xi.x; qy[r] = xi.y;
    qs[r] = xi.x * xi.x + xi.y * xi.y;
    float tv = t_arr ? t_arr[i0 + r]
                     : fminf(fmaxf((2.0f * TGT / (float)N) * __expf(0.5f * qs[r]), 1e-3f), 8.0f);
    lim[r] = __float_as_uint(tv);
  }
  if (tid < ROWS) s_tf[tid] = __uint_as_float(lim[tid]);
  __syncthreads();

  // ---- main pass: stream all N once (prefetch depth 2); push (d2_bits, idx) if bits < lim ----
  {
    const int IT = N / BLOCK;  // 48
    float4 cur = x4[tid];
    float4 n1 = x4[BLOCK + tid];
    for (int it = 0; it < IT; ++it) {
      float4 n2 = (it + 2 < IT) ? x4[(it + 2) * BLOCK + tid] : cur;
      int j = it * BLOCK + tid;
      float sqj = cur.x * cur.x + cur.y * cur.y;
#pragma unroll
      for (int r = 0; r < ROWS; ++r) {
        float dot = qx[r] * cur.x + qy[r] * cur.y;
        float d2 = fmaxf(qs[r] + sqj - 2.0f * dot, 1e-30f);
        unsigned bits = __float_as_uint(d2);
        if (bits < lim[r]) {
          int pos = atomicAdd(&s_count[r], 1);
          if (pos < CAP)
            s_cand[r][pos] = (((unsigned long long)bits) << 32) | (unsigned long long)(unsigned)j;
        }
      }
      cur = n1;
      n1 = n2;
    }
  }

  // ---- fallback (cold, ~never: P(count outside [KNN,CAP]) ~ 1e-7 per row) ----
  for (int pass = 0; pass < 6; ++pass) {
    __syncthreads();
    unsigned mask = 0;
#pragma unroll
    for (int r = 0; r < ROWS; ++r) {
      int C = s_count[r];
      if (C < KNN || C > CAP) mask |= 1u << r;
    }
    if (!mask) break;  // uniform (s_count read after barrier)
    if (tid == 0) {
#pragma unroll
      for (int r = 0; r < ROWS; ++r) {
        int C = s_count[r];
        if (C < KNN)
          s_tf[r] = fminf(s_tf[r] * fminf(fmaxf(96.0f / (float)(C > 0 ? C : 1), 3.0f), 16.0f), 64.0f);
        else if (C > CAP)
          s_tf[r] = s_tf[r] * fmaxf(64.0f / (float)C, 0.05f);
      }
    }
    __syncthreads();
    if (tid < ROWS && ((mask >> tid) & 1)) s_count[tid] = 0;
    __syncthreads();
    for (int it = 0; it < N / BLOCK; ++it) {
      int j = it * BLOCK + tid;
      float4 xj = x4[j];
      float sqj = xj.x * xj.x + xj.y * xj.y;
#pragma unroll
      for (int r = 0; r < ROWS; ++r) {
        if ((mask >> r) & 1) {
          float dot = qx[r] * xj.x + qy[r] * xj.y;
          float d2 = fmaxf(qs[r] + sqj - 2.0f * dot, 1e-30f);
          if (d2 < s_tf[r]) {
            int pos = atomicAdd(&s_count[r], 1);
            if (pos < CAP)
              s_cand[r][pos] =
                  (((unsigned long long)__float_as_uint(d2)) << 32) | (unsigned long long)(unsigned)j;
          }
        }
      }
    }
  }
  __syncthreads();

  // ---- exact rank selection: wave wid ranks row wid (broadcast inner reads; ties -> smaller idx) ----
  {
    const int r = wid;
    int C = s_count[r];
    if (C > CAP) C = CAP;
    for (int c = lane; c < C; c += 64) {
      unsigned long long mine = s_cand[r][c];
      int rank = 0;
      for (int q = 0; q < C; ++q) rank += (s_cand[r][q] < mine) ? 1 : 0;
      if (rank < KNN) {
        s_sel_d2[r][rank] = __uint_as_float((unsigned)(mine >> 32));
        s_sel_i[r][rank] = (int)(unsigned)(mine & 0xffffffffull);
      }
    }
  }
  __syncthreads();

  // ---- accumulate: wave wid handles row wid; block-local partials only ----
  {
    const int r = wid;
    const int i = i0 + r;
    float w = 0.0f, wy = 0.0f, wm = 0.0f;
    if (lane < KNN) {
      int idx = s_sel_i[r][lane];
      float dist = sqrtf(s_sel_d2[r][lane]);  // == reference sqrt(max(d2,1e-30))
      w = expf(-0.1f * dist);
      wy = w * y[idx];
      wm = w * m[idx];
    }
    for (int off = 32; off > 0; off >>= 1) {
      w  += __shfl_down(w, off, 64);
      wy += __shfl_down(wy, off, 64);
      wm += __shfl_down(wm, off, 64);
    }
    if (lane == 0) {
      double yi = (double)y[i], mi = (double)m[i];
      s_part[wid][0] = (double)w;
      s_part[wid][1] = yi * (double)wy;
      s_part[wid][2] = yi * (double)w + (double)wy;
      s_part[wid][3] = mi * (double)wm;
      s_part[wid][4] = mi * (double)w + (double)wm;
    }
  }
  __syncthreads();

  // ---- one set of 9 atomics per block into a hashed slot ----
  if (tid < 9) {
    double val;
    if (tid < 4) {
      val = s_ysum[tid];
    } else {
      val = 0.0;
      for (int w = 0; w < BLOCK / 64; ++w) val += s_part[w][tid - 4];
    }
    int base = (blockIdx.x & (NSLOT - 1)) * 16;
    atomicAdd(&ws[base + tid], val);
  }
}

__global__ __launch_bounds__(128) void finalize_kernel(const double* __restrict__ ws,
                                                       float* __restrict__ out, int N) {
  __shared__ double part[2][9];
  int tid = threadIdx.x;  // 128 threads = NSLOT
  double v[9];
#pragma unroll
  for (int c = 0; c < 9; ++c) v[c] = ws[tid * 16 + c];
#pragma unroll
  for (int c = 0; c < 9; ++c)
    for (int off = 32; off > 0; off >>= 1) v[c] += __shfl_down(v[c], off, 64);
  if ((tid & 63) == 0)
#pragma unroll
    for (int c = 0; c < 9; ++c) part[tid >> 6][c] = v[c];
  __syncthreads();
  if (tid == 0) {
    double t[9];
#pragma unroll
    for (int c = 0; c < 9; ++c) t[c] = part[0][c] + part[1][c];
    double sy = t[0], sy2 = t[1], sm = t[2], sm2 = t[3];
    double W = t[4], S1y = t[5], S2y = t[6], S1m = t[7], S2m = t[8];
    double muy = sy / (double)N, mum = sm / (double)N;
    double deny = sy2 - sy * sy / (double)N;
    double denm = sm2 - sm * sm / (double)N;
    double numy = S1y - muy * S2y + muy * muy * W;
    double numm = S1m - mum * S2m + mum * mum * W;
    out[0] = (float)((double)N / W * numy / deny);
    out[1] = (float)((double)N / W * numm / denm);
  }
}

extern "C" void kernel_launch(void* const* d_in, const int* in_sizes, int n_in,
                              void* d_out, int out_size, void* d_ws, size_t ws_size,
                              hipStream_t stream) {
  const float4* x4 = (const float4*)d_in[0];  // (1, N, 4)
  const float* y   = (const float*)d_in[1];   // (1, N, 1)
  const float* mu  = (const float*)d_in[2];   // (1, N, 1)
  float* out = (float*)d_out;
  int N = in_sizes[1];  // 12288; divisible by ROWS and BLOCK
  double* ws = (double*)d_ws;

  size_t acc_bytes = (size_t)NSLOT * 16 * sizeof(double);
  bool have_t = ws_size >= acc_bytes + (size_t)N * sizeof(float);
  float* t_arr = have_t ? (float*)((char*)d_ws + acc_bytes) : nullptr;

  hipMemsetAsync(d_ws, 0, acc_bytes, stream);
  if (have_t) thresh_kernel<<<(N + BLOCK - 1) / BLOCK, BLOCK, 0, stream>>>(x4, t_arr, N);
  knn_moran_kernel<<<N / ROWS, BLOCK, 0, stream>>>(x4, y, mu, ws, t_arr, N);
  finalize_kernel<<<1, 128, 0, stream>>>(ws, out, N);
}

// Round 13
// 194.181 us; speedup vs baseline: 1.0051x; 1.0051x over previous
//
#include <hip/hip_runtime.h>

#define KNN 32
#define BLOCK 256
#define ROWS 4
#define CAP 256
#define NSLOT 128
#define TGT 64.0f

// ws layout:
//   [0 .. NSLOT*16) doubles: hashed accumulator slots, per slot c:
//     c=0..3: sum_y, sum_y2, sum_m, sum_m2
//     c=4: W   c=5: S1y=sum w*y_i*y_k  c=6: S2y=sum w*(y_i+y_k)  c=7: S1m  c=8: S2m
//   then float t_arr[N]: per-point d2 search threshold
// moran num_y = S1y - mu_y*S2y + mu_y^2*W  (mean-free expansion; exact in f64)

__device__ inline float bessel_i0f(float z) {
  if (z < 3.75f) {
    float u = z * z * (1.0f / (3.75f * 3.75f));
    return 1.0f + u * (3.5156229f + u * (3.0899424f + u * (1.2067492f +
                  u * (0.2659732f + u * (0.0360768f + u * 0.0045813f)))));
  } else {
    float w = 3.75f / z;
    float p = 0.39894228f + w * (0.01328592f + w * (0.00225319f + w * (-0.00157565f +
              w * (0.00916281f + w * (-0.02057706f + w * (0.02635537f +
              w * (-0.01647633f + w * 0.00392377f)))))));
    return __expf(z) * p * __frsqrt_rn(z);
  }
}

// d2-threshold t with E[#points: d2<t] ~= TGT for query at |q|^2=qs, points ~ N(0,I2):
// E(t) = (N/2) e^{-qs/2} * Int_0^t e^{-s/2} I0(|q| sqrt(s)) ds  (16-pt midpoint, 2 fixed-point iters)
__device__ inline float knn_threshold(float qs, int N) {
  float t = fminf(fmaxf((2.0f * TGT / (float)N) * __expf(0.5f * qs), 1e-3f), 12.0f);
  float aq = sqrtf(qs);
#pragma unroll
  for (int nit = 0; nit < 2; ++nit) {
    float dt = t * (1.0f / 16.0f);
    float acc = 0.0f;
#pragma unroll
    for (int k = 0; k < 16; ++k) {
      float s = ((float)k + 0.5f) * dt;
      acc += __expf(-0.5f * s) * bessel_i0f(aq * sqrtf(s));
    }
    float E = 0.5f * (float)N * __expf(-0.5f * qs) * acc * dt;
    t = fminf(fmaxf(t * (TGT / fmaxf(E, 1.0f)), 1e-3f), 32.0f);
  }
  return t;
}

__global__ __launch_bounds__(BLOCK) void thresh_kernel(const float4* __restrict__ x4,
                                                       float* __restrict__ t_arr, int N) {
  int j = blockIdx.x * BLOCK + threadIdx.x;
  if (j < N) {
    float4 xi = x4[j];
    float qs = xi.x * xi.x + xi.y * xi.y;
    t_arr[j] = knn_threshold(qs, N);
  }
}

// NOTE: no per-thread arrays anywhere in this kernel (rule: runtime-indexed
// register arrays are demoted to scratch). All query state is named scalars.
__global__ void knn_moran_kernel(const float4* __restrict__ x4,
                                 const float* __restrict__ y,
                                 const float* __restrict__ m,
                                 double* __restrict__ ws,
                                 const float* __restrict__ t_arr, int N) {
  __shared__ unsigned long long s_cand[ROWS][CAP];
  __shared__ int s_count[ROWS];
  __shared__ float s_tf[ROWS];  // fallback thresholds (cold path), LDS-resident
  __shared__ float s_sel_d2[ROWS][KNN];
  __shared__ int s_sel_i[ROWS][KNN];
  __shared__ double s_part[BLOCK / 64][5];
  __shared__ double s_ysum[4];

  const int i0 = blockIdx.x * ROWS;
  const int tid = threadIdx.x;
  const int lane = tid & 63;
  const int wid = tid >> 6;

  if (tid < ROWS) s_count[tid] = 0;

  // fold this block's slice of the global y/m sums (4 elements)
  if (tid < ROWS) {
    double yv = (double)y[i0 + tid], mv = (double)m[i0 + tid];
    double a = yv, b = yv * yv, c = mv, d = mv * mv;
    for (int off = 2; off > 0; off >>= 1) {
      a += __shfl_down(a, off, 4);
      b += __shfl_down(b, off, 4);
      c += __shfl_down(c, off, 4);
      d += __shfl_down(d, off, 4);
    }
    if (tid == 0) { s_ysum[0] = a; s_ysum[1] = b; s_ysum[2] = c; s_ysum[3] = d; }
  }

  // query state: NAMED SCALARS (never an array)
  float4 xq0 = x4[i0 + 0], xq1 = x4[i0 + 1], xq2 = x4[i0 + 2], xq3 = x4[i0 + 3];
  const float qx0 = xq0.x, qy0 = xq0.y, qs0 = qx0 * qx0 + qy0 * qy0;
  const float qx1 = xq1.x, qy1 = xq1.y, qs1 = qx1 * qx1 + qy1 * qy1;
  const float qx2 = xq2.x, qy2 = xq2.y, qs2 = qx2 * qx2 + qy2 * qy2;
  const float qx3 = xq3.x, qy3 = xq3.y, qs3 = qx3 * qx3 + qy3 * qy3;
#define TV(QS, R) (t_arr ? t_arr[i0 + R] \
                         : fminf(fmaxf((2.0f * TGT / (float)N) * __expf(0.5f * (QS)), 1e-3f), 8.0f))
  const unsigned lim0 = __float_as_uint(TV(qs0, 0));
  const unsigned lim1 = __float_as_uint(TV(qs1, 1));
  const unsigned lim2 = __float_as_uint(TV(qs2, 2));
  const unsigned lim3 = __float_as_uint(TV(qs3, 3));
#undef TV
  if (tid == 0) {
    s_tf[0] = __uint_as_float(lim0);
    s_tf[1] = __uint_as_float(lim1);
    s_tf[2] = __uint_as_float(lim2);
    s_tf[3] = __uint_as_float(lim3);
  }
  __syncthreads();

  // ---- main pass: stream all N once (prefetch depth 2); push (d2_bits, idx) if bits < lim ----
#define ROW_TEST(R)                                                                         \
  {                                                                                         \
    float dot = qx##R * cur.x + qy##R * cur.y;                                              \
    float d2 = fmaxf(qs##R + sqj - 2.0f * dot, 1e-30f);                                     \
    unsigned bits = __float_as_uint(d2);                                                    \
    if (bits < lim##R) {                                                                    \
      int pos = atomicAdd(&s_count[R], 1);                                                  \
      if (pos < CAP)                                                                        \
        s_cand[R][pos] = (((unsigned long long)bits) << 32) | (unsigned long long)(unsigned)j; \
    }                                                                                       \
  }
  {
    const int IT = N / BLOCK;  // 48
    float4 cur = x4[tid];
    float4 n1 = x4[BLOCK + tid];
    for (int it = 0; it < IT; ++it) {
      float4 n2 = (it + 2 < IT) ? x4[(it + 2) * BLOCK + tid] : cur;
      int j = it * BLOCK + tid;
      float sqj = cur.x * cur.x + cur.y * cur.y;
      ROW_TEST(0)
      ROW_TEST(1)
      ROW_TEST(2)
      ROW_TEST(3)
      cur = n1;
      n1 = n2;
    }
  }
#undef ROW_TEST

  // ---- fallback (cold, ~never: P(count outside [KNN,CAP]) ~ 1e-7 per row) ----
  for (int pass = 0; pass < 6; ++pass) {
    __syncthreads();
    unsigned mask = 0;
#pragma unroll
    for (int r = 0; r < ROWS; ++r) {
      int C = s_count[r];
      if (C < KNN || C > CAP) mask |= 1u << r;
    }
    if (!mask) break;  // uniform (s_count read after barrier)
    if (tid == 0) {
#pragma unroll
      for (int r = 0; r < ROWS; ++r) {
        int C = s_count[r];
        if (C < KNN)
          s_tf[r] = fminf(s_tf[r] * fminf(fmaxf(96.0f / (float)(C > 0 ? C : 1), 3.0f), 16.0f), 64.0f);
        else if (C > CAP)
          s_tf[r] = s_tf[r] * fmaxf(64.0f / (float)C, 0.05f);
      }
    }
    __syncthreads();
    if (tid < ROWS && ((mask >> tid) & 1)) s_count[tid] = 0;
    __syncthreads();
#define ROW_RESCAN(R)                                                                       \
  if ((mask >> R) & 1) {                                                                    \
    float dot = qx##R * xj.x + qy##R * xj.y;                                                \
    float d2 = fmaxf(qs##R + sqj - 2.0f * dot, 1e-30f);                                     \
    if (d2 < s_tf[R]) {                                                                     \
      int pos = atomicAdd(&s_count[R], 1);                                                  \
      if (pos < CAP)                                                                        \
        s_cand[R][pos] = (((unsigned long long)__float_as_uint(d2)) << 32) |                \
                         (unsigned long long)(unsigned)j;                                   \
    }                                                                                       \
  }
    for (int it = 0; it < N / BLOCK; ++it) {
      int j = it * BLOCK + tid;
      float4 xj = x4[j];
      float sqj = xj.x * xj.x + xj.y * xj.y;
      ROW_RESCAN(0)
      ROW_RESCAN(1)
      ROW_RESCAN(2)
      ROW_RESCAN(3)
    }
#undef ROW_RESCAN
  }
  __syncthreads();

  // ---- exact rank selection: wave wid ranks row wid (LDS broadcast reads; ties -> smaller idx) ----
  {
    const int r = wid;  // LDS index, dynamic is fine
    int C = s_count[r];
    if (C > CAP) C = CAP;
    for (int c = lane; c < C; c += 64) {
      unsigned long long mine = s_cand[r][c];
      int rank = 0;
      for (int q = 0; q < C; ++q) rank += (s_cand[r][q] < mine) ? 1 : 0;
      if (rank < KNN) {
        s_sel_d2[r][rank] = __uint_as_float((unsigned)(mine >> 32));
        s_sel_i[r][rank] = (int)(unsigned)(mine & 0xffffffffull);
      }
    }
  }
  __syncthreads();

  // ---- accumulate: wave wid handles row wid; block-local partials only ----
  {
    const int r = wid;
    const int i = i0 + r;
    float w = 0.0f, wy = 0.0f, wm = 0.0f;
    if (lane < KNN) {
      int idx = s_sel_i[r][lane];
      float dist = sqrtf(s_sel_d2[r][lane]);  // == reference sqrt(max(d2,1e-30))
      w = expf(-0.1f * dist);
      wy = w * y[idx];
      wm = w * m[idx];
    }
    for (int off = 32; off > 0; off >>= 1) {
      w  += __shfl_down(w, off, 64);
      wy += __shfl_down(wy, off, 64);
      wm += __shfl_down(wm, off, 64);
    }
    if (lane == 0) {
      double yi = (double)y[i], mi = (double)m[i];
      s_part[wid][0] = (double)w;
      s_part[wid][1] = yi * (double)wy;
      s_part[wid][2] = yi * (double)w + (double)wy;
      s_part[wid][3] = mi * (double)wm;
      s_part[wid][4] = mi * (double)w + (double)wm;
    }
  }
  __syncthreads();

  // ---- one set of 9 atomics per block into a hashed slot ----
  if (tid < 9) {
    double val;
    if (tid < 4) {
      val = s_ysum[tid];
    } else {
      val = 0.0;
      for (int w = 0; w < BLOCK / 64; ++w) val += s_part[w][tid - 4];
    }
    int base = (blockIdx.x & (NSLOT - 1)) * 16;
    atomicAdd(&ws[base + tid], val);
  }
}

__global__ __launch_bounds__(128) void finalize_kernel(const double* __restrict__ ws,
                                                       float* __restrict__ out, int N) {
  __shared__ double part[2][9];
  int tid = threadIdx.x;  // 128 threads = NSLOT
  double v[9];
#pragma unroll
  for (int c = 0; c < 9; ++c) v[c] = ws[tid * 16 + c];
#pragma unroll
  for (int c = 0; c < 9; ++c)
    for (int off = 32; off > 0; off >>= 1) v[c] += __shfl_down(v[c], off, 64);
  if ((tid & 63) == 0)
#pragma unroll
    for (int c = 0; c < 9; ++c) part[tid >> 6][c] = v[c];
  __syncthreads();
  if (tid == 0) {
    double t[9];
#pragma unroll
    for (int c = 0; c < 9; ++c) t[c] = part[0][c] + part[1][c];
    double sy = t[0], sy2 = t[1], sm = t[2], sm2 = t[3];
    double W = t[4], S1y = t[5], S2y = t[6], S1m = t[7], S2m = t[8];
    double muy = sy / (double)N, mum = sm / (double)N;
    double deny = sy2 - sy * sy / (double)N;
    double denm = sm2 - sm * sm / (double)N;
    double numy = S1y - muy * S2y + muy * muy * W;
    double numm = S1m - mum * S2m + mum * mum * W;
    out[0] = (float)((double)N / W * numy / deny);
    out[1] = (float)((double)N / W * numm / denm);
  }
}

extern "C" void kernel_launch(void* const* d_in, const int* in_sizes, int n_in,
                              void* d_out, int out_size, void* d_ws, size_t ws_size,
                              hipStream_t stream) {
  const float4* x4 = (const float4*)d_in[0];  // (1, N, 4)
  const float* y   = (const float*)d_in[1];   // (1, N, 1)
  const float* mu  = (const float*)d_in[2];   // (1, N, 1)
  float* out = (float*)d_out;
  int N = in_sizes[1];  // 12288; divisible by ROWS and BLOCK
  double* ws = (double*)d_ws;

  size_t acc_bytes = (size_t)NSLOT * 16 * sizeof(double);
  bool have_t = ws_size >= acc_bytes + (size_t)N * sizeof(float);
  float* t_arr = have_t ? (float*)((char*)d_ws + acc_bytes) : nullptr;

  hipMemsetAsync(d_ws, 0, acc_bytes, stream);
  if (have_t) thresh_kernel<<<(N + BLOCK - 1) / BLOCK, BLOCK, 0, stream>>>(x4, t_arr, N);
  knn_moran_kernel<<<N / ROWS, BLOCK, 0, stream>>>(x4, y, mu, ws, t_arr, N);
  finalize_kernel<<<1, 128, 0, stream>>>(ws, out, N);
}

// Round 14
// 135.393 us; speedup vs baseline: 1.4415x; 1.4342x over previous
//
#include <hip/hip_runtime.h>

#define KNN 32
#define BLOCK 256
#define ROWS 8
#define NBINS 256
#define HPAD 8
#define CAP 320
#define SUBN 3072   // pass-1 subsample: first SUBN points (subset argument keeps the >=KNN guarantee)
#define SOPT 14     // optimistic sub-cum target: full-count mean ~= 4*SOPT = 56, P(<KNN) ~ 3e-5/row
#define BMIN 288    // d2-bin offset: bin = clamp((bits(d2)>>21)-BMIN, 0, NBINS-1)
#define NSLOT 128   // hashed accumulator slots (16 doubles stride each)

// ws (f64), per slot s at ws[s*16 + c]:
//   c=0..3: sum_y, sum_y2, sum_m, sum_m2
//   c=4: W   c=5: S1y=sum w*y_i*y_k   c=6: S2y=sum w*(y_i+y_k)   c=7: S1m   c=8: S2m
// moran num_y = S1y - mu_y*S2y + mu_y^2*W  (mean-free expansion; exact in f64)

__global__ __launch_bounds__(BLOCK, 5) void knn_moran_kernel(const float4* __restrict__ x4,
                                                             const float* __restrict__ y,
                                                             const float* __restrict__ m,
                                                             double* __restrict__ ws, int N) {
  __shared__ int s_hist[ROWS][NBINS + HPAD];
  __shared__ unsigned long long s_cand[ROWS][CAP];
  __shared__ int s_count[ROWS];
  __shared__ int s_Topt[ROWS];
  __shared__ int s_Tsafe[ROWS];
  __shared__ int s_fail;
  __shared__ float s_sel_d2[ROWS][KNN];
  __shared__ int s_sel_i[ROWS][KNN];
  __shared__ double s_part[BLOCK / 64][5];
  __shared__ double s_ysum[4];

  const int i0 = blockIdx.x * ROWS;
  const int tid = threadIdx.x;
  const int lane = tid & 63;
  const int wid = tid >> 6;

  for (int b = tid; b < ROWS * (NBINS + HPAD); b += BLOCK) ((int*)s_hist)[b] = 0;
  if (tid < ROWS) s_count[tid] = 0;
  if (tid == 0) s_fail = 0;

  // fold this block's slice of the global y/m sums (8 elements)
  if (tid < ROWS) {
    double yv = (double)y[i0 + tid], mv = (double)m[i0 + tid];
    double a = yv, b = yv * yv, c = mv, d = mv * mv;
    for (int off = 4; off > 0; off >>= 1) {
      a += __shfl_down(a, off, 8);
      b += __shfl_down(b, off, 8);
      c += __shfl_down(c, off, 8);
      d += __shfl_down(d, off, 8);
    }
    if (tid == 0) { s_ysum[0] = a; s_ysum[1] = b; s_ysum[2] = c; s_ysum[3] = d; }
  }

  float qx[ROWS], qy[ROWS], qs[ROWS];
#pragma unroll
  for (int r = 0; r < ROWS; ++r) {
    float4 xi = x4[i0 + r];
    qx[r] = xi.x; qy[r] = xi.y;
    qs[r] = xi.x * xi.x + xi.y * xi.y;
  }
  __syncthreads();

  // ---- pass 1: subsampled (contiguous, coalesced) d2-bin histogram; prefetched ----
  {
    float4 cur = x4[tid];
    for (int it = 0; it < SUBN / BLOCK; ++it) {
      float4 nxt = (it + 1 < SUBN / BLOCK) ? x4[(it + 1) * BLOCK + tid] : cur;
      float sqj = cur.x * cur.x + cur.y * cur.y;
#pragma unroll
      for (int r = 0; r < ROWS; ++r) {
        float dot = qx[r] * cur.x + qy[r] * cur.y;
        float d2 = fmaxf(qs[r] + sqj - 2.0f * dot, 1e-30f);
        int b = (int)(__float_as_uint(d2) >> 21) - BMIN;
        b = min(max(b, 0), NBINS - 1);
        atomicAdd(&s_hist[r][b], 1);  // no return value used -> fire-and-forget, no stall
      }
      cur = nxt;
    }
  }
  __syncthreads();

  // ---- thresholds per row (wave wid scans rows 2*wid, 2*wid+1): T_opt and T_safe in one scan ----
  for (int rr = 0; rr < 2; ++rr) {
    const int r = wid * 2 + rr;
    int cnt[NBINS / 64];
    int cs = 0;
#pragma unroll
    for (int q = 0; q < NBINS / 64; ++q) {
      cnt[q] = s_hist[r][lane * (NBINS / 64) + q];
      cs += cnt[q];
    }
    int scan = cs;
    for (int off = 1; off < 64; off <<= 1) {
      int v = __shfl_up(scan, off, 64);
      if (lane >= off) scan += v;
    }
    int excl = scan - cs;
    if (excl < SOPT && scan >= SOPT) {  // unique crossing lane for SOPT
      int run = excl;
#pragma unroll
      for (int q = 0; q < NBINS / 64; ++q) {
        if (run < SOPT && run + cnt[q] >= SOPT) { s_Topt[r] = lane * (NBINS / 64) + q; break; }
        run += cnt[q];
      }
    }
    if (excl < KNN && scan >= KNN) {  // unique crossing lane for KNN
      int run = excl;
#pragma unroll
      for (int q = 0; q < NBINS / 64; ++q) {
        if (run < KNN && run + cnt[q] >= KNN) { s_Tsafe[r] = lane * (NBINS / 64) + q; break; }
        run += cnt[q];
      }
    }
  }
  __syncthreads();
  unsigned lim[ROWS], limS[ROWS];  // candidate  <=>  bits(d2) < lim
#pragma unroll
  for (int r = 0; r < ROWS; ++r) {
    lim[r]  = (s_Topt[r]  >= NBINS - 1) ? 0xFFFFFFFFu : ((unsigned)(s_Topt[r]  + BMIN + 1) << 21);
    limS[r] = (s_Tsafe[r] >= NBINS - 1) ? 0xFFFFFFFFu : ((unsigned)(s_Tsafe[r] + BMIN + 1) << 21);
  }

  // ---- pass 2: full streaming scan; SOFTWARE-PIPELINED push ----
  // The LDS atomicAdd RETURNS pos (~120-240cy round trip). Storing with it immediately
  // exposes the full latency ~every iteration (P(any push) ~ 93%). Defer the dependent
  // store by one iteration so the wait lands after ~130cy of independent row-math.
  {
    bool ppred[ROWS];
    int ppos[ROWS];
    unsigned long long pkey[ROWS];
#pragma unroll
    for (int r = 0; r < ROWS; ++r) { ppred[r] = false; ppos[r] = 0; pkey[r] = 0; }

    float4 cur = x4[tid];
    const int IT = N / BLOCK;
    for (int it = 0; it < IT; ++it) {
      float4 nxt = (it + 1 < IT) ? x4[(it + 1) * BLOCK + tid] : cur;
      int j = it * BLOCK + tid;
      float sqj = cur.x * cur.x + cur.y * cur.y;
#pragma unroll
      for (int r = 0; r < ROWS; ++r) {
        float dot = qx[r] * cur.x + qy[r] * cur.y;
        float d2 = fmaxf(qs[r] + sqj - 2.0f * dot, 1e-30f);
        unsigned bits = __float_as_uint(d2);
        bool pr = bits < lim[r];
        // store PREVIOUS iteration's candidate (its pos has long since returned)
        if (ppred[r] && ppos[r] < CAP) s_cand[r][ppos[r]] = pkey[r];
        ppred[r] = pr;
        pkey[r] = (((unsigned long long)bits) << 32) | (unsigned long long)(unsigned)j;
        if (pr) ppos[r] = atomicAdd(&s_count[r], 1);  // issue; wait deferred to next iter
      }
      cur = nxt;
    }
    // drain the pipeline
#pragma unroll
    for (int r = 0; r < ROWS; ++r)
      if (ppred[r] && ppos[r] < CAP) s_cand[r][ppos[r]] = pkey[r];
  }
  __syncthreads();

  // ---- rare fallback: rows with < KNN candidates rescan with the provably-safe threshold ----
  if (tid < ROWS && s_count[tid] < KNN) atomicOr(&s_fail, 1 << tid);
  __syncthreads();
  const int failmask = s_fail;  // uniform
  if (failmask) {
    if (tid < ROWS && ((failmask >> tid) & 1)) s_count[tid] = 0;
    __syncthreads();
    const int IT2 = N / BLOCK;
    for (int it = 0; it < IT2; ++it) {
      int j = it * BLOCK + tid;
      float4 xj = x4[j];
      float sqj = xj.x * xj.x + xj.y * xj.y;
#pragma unroll
      for (int r = 0; r < ROWS; ++r) {
        if ((failmask >> r) & 1) {
          float dot = qx[r] * xj.x + qy[r] * xj.y;
          float d2 = fmaxf(qs[r] + sqj - 2.0f * dot, 1e-30f);
          unsigned bits = __float_as_uint(d2);
          if (bits < limS[r]) {
            int pos = atomicAdd(&s_count[r], 1);
            if (pos < CAP)
              s_cand[r][pos] = (((unsigned long long)bits) << 32) | (unsigned long long)(unsigned)j;
          }
        }
      }
    }
    __syncthreads();
  }

  // ---- exact rank selection per row on (d2_bits, idx) keys (ties -> smaller idx, == top_k) ----
  for (int r = 0; r < ROWS; ++r) {
    int C = s_count[r];
    if (C > CAP) C = CAP;
    for (int c = tid; c < C; c += BLOCK) {
      unsigned long long mine = s_cand[r][c];
      int rank = 0;
      for (int q = 0; q < C; ++q) rank += (s_cand[r][q] < mine) ? 1 : 0;
      if (rank < KNN) {
        s_sel_d2[r][rank] = __uint_as_float((unsigned)(mine >> 32));
        s_sel_i[r][rank] = (int)(unsigned)(mine & 0xffffffffull);
      }
    }
  }
  __syncthreads();

  // ---- accumulate: wave wid handles rows 2*wid, 2*wid+1; block-local partials only ----
  {
    double pW = 0.0, pS1y = 0.0, pS2y = 0.0, pS1m = 0.0, pS2m = 0.0;
    for (int rr = 0; rr < 2; ++rr) {
      const int r = wid * 2 + rr;
      const int i = i0 + r;
      float w = 0.0f, wy = 0.0f, wm = 0.0f;
      if (lane < KNN) {
        int idx = s_sel_i[r][lane];
        float dist = sqrtf(s_sel_d2[r][lane]);  // == reference sqrt(max(d2,1e-30))
        w = expf(-0.1f * dist);
        wy = w * y[idx];
        wm = w * m[idx];
      }
      for (int off = 32; off > 0; off >>= 1) {
        w  += __shfl_down(w, off, 64);
        wy += __shfl_down(wy, off, 64);
        wm += __shfl_down(wm, off, 64);
      }
      if (lane == 0) {
        double yi = (double)y[i], mi = (double)m[i];
        pW   += (double)w;
        pS1y += yi * (double)wy;
        pS2y += yi * (double)w + (double)wy;
        pS1m += mi * (double)wm;
        pS2m += mi * (double)w + (double)wm;
      }
    }
    if (lane == 0) {
      s_part[wid][0] = pW; s_part[wid][1] = pS1y; s_part[wid][2] = pS2y;
      s_part[wid][3] = pS1m; s_part[wid][4] = pS2m;
    }
  }
  __syncthreads();

  // ---- one set of 9 atomics per block into a hashed slot ----
  if (tid < 9) {
    double val;
    if (tid < 4) {
      val = s_ysum[tid];
    } else {
      val = 0.0;
      for (int w = 0; w < BLOCK / 64; ++w) val += s_part[w][tid - 4];
    }
    int base = (blockIdx.x & (NSLOT - 1)) * 16;
    atomicAdd(&ws[base + tid], val);
  }
}

__global__ __launch_bounds__(128) void finalize_kernel(const double* __restrict__ ws,
                                                       float* __restrict__ out, int N) {
  __shared__ double part[2][9];
  int tid = threadIdx.x;  // 128 threads = NSLOT
  double v[9];
#pragma unroll
  for (int c = 0; c < 9; ++c) v[c] = ws[tid * 16 + c];
#pragma unroll
  for (int c = 0; c < 9; ++c)
    for (int off = 32; off > 0; off >>= 1) v[c] += __shfl_down(v[c], off, 64);
  if ((tid & 63) == 0)
#pragma unroll
    for (int c = 0; c < 9; ++c) part[tid >> 6][c] = v[c];
  __syncthreads();
  if (tid == 0) {
    double t[9];
#pragma unroll
    for (int c = 0; c < 9; ++c) t[c] = part[0][c] + part[1][c];
    double sy = t[0], sy2 = t[1], sm = t[2], sm2 = t[3];
    double W = t[4], S1y = t[5], S2y = t[6], S1m = t[7], S2m = t[8];
    double muy = sy / (double)N, mum = sm / (double)N;
    double deny = sy2 - sy * sy / (double)N;
    double denm = sm2 - sm * sm / (double)N;
    double numy = S1y - muy * S2y + muy * muy * W;
    double numm = S1m - mum * S2m + mum * mum * W;
    out[0] = (float)((double)N / W * numy / deny);
    out[1] = (float)((double)N / W * numm / denm);
  }
}

extern "C" void kernel_launch(void* const* d_in, const int* in_sizes, int n_in,
                              void* d_out, int out_size, void* d_ws, size_t ws_size,
                              hipStream_t stream) {
  const float4* x4 = (const float4*)d_in[0];  // (1, N, 4)
  const float* y   = (const float*)d_in[1];   // (1, N, 1)
  const float* mu  = (const float*)d_in[2];   // (1, N, 1)
  float* out = (float*)d_out;
  int N = in_sizes[1];  // 12288; divisible by ROWS, BLOCK, SUBN
  double* ws = (double*)d_ws;

  hipMemsetAsync(d_ws, 0, (size_t)NSLOT * 16 * sizeof(double), stream);
  knn_moran_kernel<<<N / ROWS, BLOCK, 0, stream>>>(x4, y, mu, ws, N);
  finalize_kernel<<<1, 128, 0, stream>>>(ws, out, N);
}